// Round 9
// baseline (372.988 us; speedup 1.0000x reference)
//
#include <hip/hip_runtime.h>
#include <cstdint>
#include <cstddef>

#define S_LEN 2048
#define DM    4096
#define NH    32
#define NKV   8
#define HDIM  128
#define EQ    4096   // NH*HDIM
#define EKV   1024   // NKV*HDIM
#define SC_LOG2E 0.1275325477889277f   // (1/sqrt(128)) * log2(e)

typedef unsigned short u16;
typedef short bf16x8 __attribute__((ext_vector_type(8)));
typedef float f32x4  __attribute__((ext_vector_type(4)));

__device__ __forceinline__ u16 f2bf(float f) {
  union { float f; unsigned u; } v; v.f = f;
  unsigned r = v.u + 0x7FFFu + ((v.u >> 16) & 1u);
  return (u16)(r >> 16);
}
__device__ __forceinline__ float bf2f(u16 b) {
  union { unsigned u; float f; } v; v.u = ((unsigned)b) << 16;
  return v.f;
}
// HW packed fp32->bf16 RNE (same ties-even rounding as f2bf)
__device__ __forceinline__ unsigned cvt2bf(float lo, float hi) {
  unsigned r;
  asm("v_cvt_pk_bf16_f32 %0, %1, %2" : "=v"(r) : "v"(lo), "v"(hi));
  return r;
}
__device__ __forceinline__ void glds16(const void* g, void* l) {
  __builtin_amdgcn_global_load_lds((const __attribute__((address_space(1))) void*)g,
                                   (__attribute__((address_space(3))) void*)l, 16, 0, 0);
}

// ---------------------------------------------------------------- cast fp32->bf16 (x only)
__global__ void cast_x(const float* __restrict__ x, u16* __restrict__ xb) {
  const size_t stride = (size_t)gridDim.x * blockDim.x;
  for (size_t i = (size_t)blockIdx.x * blockDim.x + threadIdx.x; i < 2097152u; i += stride) {
    float4 f = ((const float4*)x)[i];
    ushort4 b;
    b.x = f2bf(f.x); b.y = f2bf(f.y); b.z = f2bf(f.z); b.w = f2bf(f.w);
    ((ushort4*)xb)[i] = b;
  }
}

// ---------------------------------------------------------------- 2-phase GEMM, BM=128, BN=64*NF
// C = A * B^T. A bf16 row-major (glds-staged); B staged DIRECTLY FROM FP32
// weights: global_load fp32 -> v_cvt_pk_bf16_f32 -> swizzled ds_write_b128
// (T14 async split: loads for tile t+2 issued before compute(t), consumed by
// ds_write next iteration; compiler inserts the vmcnt before reg use).
// 4 waves (2x2), wave-tile 64 x 32*NF, BK=64, double-buffered (80/64 KB ->
// 2 blocks/CU = 2 waves/SIMD; >=2/SIMD is a hard floor per R7). One
// __syncthreads per K-tile (drains glds + reg-loads + ds_writes + readers).
// XOR swizzle u^=(row&7) on 16B units: A via pre-swizzled global source
// (linear glds dest); B via swizzled ds_write addr; both read swizzled.
template<int UN>
__device__ __forceinline__ void stage_t(const u16* __restrict__ g, int ldg, int k0,
                                        u16* ldsp, int t) {
  const int wb = t & ~63;
#pragma unroll
  for (int j = 0; j < UN / 256; ++j) {
    const int U = j * 256 + t;
    const int row = U >> 3, u = U & 7;
    const int uu = u ^ (row & 7);
    glds16(g + (size_t)row * ldg + k0 + uu * 8, ldsp + (size_t)(j * 256 + wb) * 8);
  }
}

template<int NF, bool QKV3>
__global__ __launch_bounds__(256, 2)
void gemm2p(const u16* __restrict__ A,
            const float* __restrict__ Bq, const float* __restrict__ Bk,
            const float* __restrict__ Bv,
            void* __restrict__ Cq, u16* __restrict__ Ck, u16* __restrict__ Cv,
            int K) {
  constexpr int BN = 64 * NF;
  constexpr int AT = 128 * 64;        // u16 per A tile (8192)
  constexpr int BT = BN * 64;         // u16 per B tile
  constexpr int NU = BN / 32;         // 16B-units per thread for B (6 or 4)
  __shared__ u16 lds[2 * (AT + BT)];  // A0 @0, A1 @AT, B0 @2*AT, B1 @2*AT+BT
  const int t = threadIdx.x;
  const int l = t & 63, lr = l & 15, lg = l >> 4;
  const int wid = t >> 6, wm = wid >> 1, wn = wid & 1;
  const int m0 = blockIdx.y * 128, n0 = blockIdx.x * BN;
  const int KT = K >> 6;

  const u16* Ab = A + (size_t)m0 * K;

  // per-thread B unit geometry (fixed across tiles)
  const float* bptr[NU];
  int bswz[NU];
#pragma unroll
  for (int j = 0; j < NU; ++j) {
    const int U = j * 256 + t;
    const int brow = U >> 3, u = U & 7;
    const int gr = n0 + brow;
    const float* bp;
    if constexpr (QKV3) {
      if (gr < 4096)      bp = Bq + (size_t)gr * K;
      else if (gr < 5120) bp = Bk + (size_t)(gr - 4096) * K;
      else                bp = Bv + (size_t)(gr - 5120) * K;
    } else {
      bp = Bq + (size_t)gr * K;
    }
    bptr[j] = bp + u * 8;
    bswz[j] = brow * 64 + (u ^ (brow & 7)) * 8;
  }

  float4 blo[NU], bhi[NU];
#define LOADB(KT_IDX) { \
  const int k0_ = (KT_IDX) * 64; \
  _Pragma("unroll") \
  for (int j = 0; j < NU; ++j) { \
    blo[j] = *(const float4*)&bptr[j][k0_]; \
    bhi[j] = *(const float4*)&bptr[j][k0_ + 4]; \
  } }
#define WRITEB(BUF) { \
  _Pragma("unroll") \
  for (int j = 0; j < NU; ++j) { \
    uint4 pk; \
    pk.x = cvt2bf(blo[j].x, blo[j].y); \
    pk.y = cvt2bf(blo[j].z, blo[j].w); \
    pk.z = cvt2bf(bhi[j].x, bhi[j].y); \
    pk.w = cvt2bf(bhi[j].z, bhi[j].w); \
    *(uint4*)&lds[2 * AT + (BUF) * BT + bswz[j]] = pk; \
  } }

  f32x4 acc[4][2 * NF] = {};

  // prologue: B(0)->regs, A(0)->buf0 glds, B(0)->buf0 ds_write, B(1)->regs
  LOADB(0);
  stage_t<1024>(Ab, K, 0, &lds[0], t);
  WRITEB(0);
  LOADB(KT > 1 ? 1 : 0);
  __syncthreads();

  int cur = 0;
#pragma unroll 1
  for (int tau = 0; tau < KT; ++tau) {
    const int nxt = (tau + 1 < KT ? tau + 1 : KT - 1);
    const int nx2 = (tau + 2 < KT ? tau + 2 : KT - 1);
    WRITEB(cur ^ 1);                                   // B(tau+1) regs -> LDS
    stage_t<1024>(Ab, K, nxt * 64, &lds[(cur ^ 1) * AT], t);  // A(tau+1) glds
    LOADB(nx2);                                        // B(tau+2) -> regs

    const int aBase = cur * AT;
    const int bBase = 2 * AT + cur * BT;

    bf16x8 af[4][2];
#pragma unroll
    for (int mf = 0; mf < 4; ++mf)
#pragma unroll
      for (int kk = 0; kk < 2; ++kk) {
        const int row = wm * 64 + mf * 16 + lr;
        const int uu = ((kk * 4 + lg) ^ (row & 7)) * 8;
        af[mf][kk] = *(const bf16x8*)&lds[aBase + row * 64 + uu];
      }

#pragma unroll
    for (int n = 0; n < 2 * NF; ++n) {
      const int brow = wn * (32 * NF) + n * 16 + lr;
      const int u0 = ((0 * 4 + lg) ^ (brow & 7)) * 8;
      const int u1 = ((1 * 4 + lg) ^ (brow & 7)) * 8;
      bf16x8 b0 = *(const bf16x8*)&lds[bBase + brow * 64 + u0];
      bf16x8 b1 = *(const bf16x8*)&lds[bBase + brow * 64 + u1];
#pragma unroll
      for (int mf = 0; mf < 4; ++mf) {
        acc[mf][n] = __builtin_amdgcn_mfma_f32_16x16x32_bf16(af[mf][0], b0, acc[mf][n], 0, 0, 0);
        acc[mf][n] = __builtin_amdgcn_mfma_f32_16x16x32_bf16(af[mf][1], b1, acc[mf][n], 0, 0, 0);
      }
    }
    __syncthreads();
    cur ^= 1;
  }

  // epilogue; fragment cols are 16-aligned so QKV routing is per-fragment
#pragma unroll
  for (int mf = 0; mf < 4; ++mf) {
    const int row = m0 + wm * 64 + mf * 16 + lg * 4;
#pragma unroll
    for (int n = 0; n < 2 * NF; ++n) {
      const int gc = n0 + wn * (32 * NF) + n * 16 + lr;
#pragma unroll
      for (int r = 0; r < 4; ++r) {
        if constexpr (QKV3) {
          if (gc < 4096)
            ((u16*)Cq)[(size_t)(row + r) * 4096 + gc] = f2bf(acc[mf][n][r]);
          else if (gc < 5120)
            Ck[(size_t)(row + r) * 1024 + (gc - 4096)] = f2bf(acc[mf][n][r]);
          else
            Cv[(size_t)(row + r) * 1024 + (gc - 5120)] = f2bf(acc[mf][n][r]);
        } else {
          ((float*)Cq)[(size_t)(row + r) * 4096 + gc] = acc[mf][n][r];
        }
      }
    }
  }
#undef LOADB
#undef WRITEB
}

// ---------------------------------------------------------------- RoPE (q then k)
__global__ void rope_all(u16* __restrict__ qd, u16* __restrict__ kd,
                         const float* __restrict__ cosb, const float* __restrict__ sinb,
                         const int* __restrict__ sidx) {
  const int u = blockIdx.x * blockDim.x + threadIdx.x;
  u16* base; int s, b;
  if (u < 1048576) {
    base = qd + (size_t)u * 8;
    s = u >> 9;
    b = u & 15;
  } else if (u < 1310720) {
    const int u2 = u - 1048576;
    base = kd + (size_t)u2 * 8;
    s = u2 >> 7;
    b = u2 & 15;
  } else return;
  const int pos = sidx[s];
  const float4 c  = *(const float4*)&cosb[pos * 64 + b * 4];
  const float4 sn = *(const float4*)&sinb[pos * 64 + b * 4];
  uint4 raw = *(uint4*)base;
  u16* pe = (u16*)&raw;
  const float cc[4] = {c.x, c.y, c.z, c.w};
  const float ss[4] = {sn.x, sn.y, sn.z, sn.w};
#pragma unroll
  for (int j = 0; j < 4; ++j) {
    const float xr = bf2f(pe[2 * j]), xi = bf2f(pe[2 * j + 1]);
    pe[2 * j]     = f2bf(xr * cc[j] - xi * ss[j]);
    pe[2 * j + 1] = f2bf(xr * ss[j] + xi * cc[j]);
  }
  *(uint4*)base = raw;
}

// ---------------------------------------------------------------- V transpose
__global__ void transpose_v(const u16* __restrict__ v, u16* __restrict__ vt) {
  __shared__ u16 tile[32][33];
  const int tx = threadIdx.x, ty = threadIdx.y;
  const int c0 = blockIdx.x * 32, s0 = blockIdx.y * 32;
#pragma unroll
  for (int j = 0; j < 32; j += 8)
    tile[ty + j][tx] = v[(size_t)(s0 + ty + j) * EKV + c0 + tx];
  __syncthreads();
#pragma unroll
  for (int j = 0; j < 32; j += 8)
    vt[(size_t)(c0 + ty + j) * S_LEN + s0 + tx] = tile[tx][ty + j];
}

// ---------------------------------------------------------------- flash attention
// Merged causal pair (p, 31-p): one KV sweep, nt = 32-p tiles. Tile B always,
// tile A while tk<=p. Dual steps share the K LDS reads: one fused QK^T loop
// reads each bk once and feeds BOTH tiles' MFMAs (-16 LDS reads/dual step).
// K/V double-buffered, one barrier per tile; 73 KB LDS -> 2 blocks/CU.
#define ATTN_STAGE(TK, BUF) { \
  const int kv0s = (TK) * 64; \
  _Pragma("unroll") \
  for (int hh = 0; hh < 4; ++hh) { \
    const int f = hh * 256 + t; \
    { const int row = f >> 4, uu = f & 15, us = uu ^ (row & 7); \
      glds16(&k[(size_t)(kv0s + row) * EKV + kvh * HDIM + us * 8], &lK[BUF][(hh * 256 + wb) * 8]); } \
    { const int row = f >> 3, uu = f & 7, us = uu ^ (row & 7); \
      glds16(&vt[(size_t)(kvh * HDIM + row) * S_LEN + kv0s + us * 8], &lV[BUF][(hh * 256 + wb) * 8]); } \
  } }

// mask/scale + online softmax + P->LDS + PV for one tile's scores SC
#define SMPV(SC, O, MR, LR, Q0) { \
  _Pragma("unroll") \
  for (int n = 0; n < 4; ++n) { \
    const int kvc = kv0 + n * 16 + lr; \
    _Pragma("unroll") \
    for (int r = 0; r < 4; ++r) { \
      const int qr = (Q0) + lg * 4 + r; \
      const float vv = SC[n][r] * SC_LOG2E; \
      SC[n][r] = (kvc > qr) ? -1e30f : vv; \
    } \
  } \
  _Pragma("unroll") \
  for (int r = 0; r < 4; ++r) { \
    float v = fmaxf(fmaxf(SC[0][r], SC[1][r]), fmaxf(SC[2][r], SC[3][r])); \
    v = fmaxf(v, __shfl_xor(v, 1)); \
    v = fmaxf(v, __shfl_xor(v, 2)); \
    v = fmaxf(v, __shfl_xor(v, 4)); \
    v = fmaxf(v, __shfl_xor(v, 8)); \
    const float mn = fmaxf(MR[r], v); \
    const float sf = __builtin_amdgcn_exp2f(MR[r] - mn); \
    MR[r] = mn; \
    float rs = 0.f; \
    _Pragma("unroll") \
    for (int n = 0; n < 4; ++n) { \
      const float pv = __builtin_amdgcn_exp2f(SC[n][r] - mn); \
      SC[n][r] = pv; \
      rs += pv; \
    } \
    rs += __shfl_xor(rs, 1); \
    rs += __shfl_xor(rs, 2); \
    rs += __shfl_xor(rs, 4); \
    rs += __shfl_xor(rs, 8); \
    LR[r] = LR[r] * sf + rs; \
    _Pragma("unroll") \
    for (int nh = 0; nh < 8; ++nh) O[nh][r] *= sf; \
  } \
  _Pragma("unroll") \
  for (int n = 0; n < 4; ++n) \
    _Pragma("unroll") \
    for (int r = 0; r < 4; ++r) \
      lPw[(lg * 4 + r) * 72 + n * 16 + lr] = f2bf(SC[n][r]); \
  _Pragma("unroll") \
  for (int kc2 = 0; kc2 < 2; ++kc2) { \
    bf16x8 pa = *(const bf16x8*)&lPw[lr * 72 + kc2 * 32 + lg * 8]; \
    _Pragma("unroll") \
    for (int nh = 0; nh < 8; ++nh) { \
      const int row = nh * 16 + lr; \
      const int us = (kc2 * 4 + lg) ^ (row & 7); \
      bf16x8 bv = *(const bf16x8*)&lVc[row * 64 + us * 8]; \
      O[nh] = __builtin_amdgcn_mfma_f32_16x16x32_bf16(pa, bv, O[nh], 0, 0, 0); \
    } \
  } }

__global__ __launch_bounds__(256, 2)
void attn_fwd(const u16* __restrict__ q, const u16* __restrict__ k,
              const u16* __restrict__ vt, u16* __restrict__ ao) {
  __shared__ u16 lK[2][64 * 128];
  __shared__ u16 lV[2][128 * 64];
  __shared__ u16 lP[4 * 16 * 72];
  const int t = threadIdx.x, w = t >> 6, l = t & 63;
  const int lr = l & 15, lg = l >> 4;
  const int wb = t & ~63;
  const int p = blockIdx.x, h = blockIdx.y;
  const int kvh = h >> 2;
  u16* lPw = &lP[w * (16 * 72)];

  const int q0A = p * 64 + w * 16;
  const int q0B = (31 - p) * 64 + w * 16;
  const int nt = 32 - p;

  bf16x8 qaA[4], qaB[4];
#pragma unroll
  for (int kc = 0; kc < 4; ++kc) {
    qaA[kc] = *(const bf16x8*)&q[(size_t)(q0A + lr) * EQ + h * HDIM + kc * 32 + lg * 8];
    qaB[kc] = *(const bf16x8*)&q[(size_t)(q0B + lr) * EQ + h * HDIM + kc * 32 + lg * 8];
  }

  f32x4 oA[8] = {}, oB[8] = {};
  float mA[4], lA[4], mB[4], lB[4];
#pragma unroll
  for (int r = 0; r < 4; ++r) { mA[r] = -1e30f; lA[r] = 0.f; mB[r] = -1e30f; lB[r] = 0.f; }

  int cur = 0;
  ATTN_STAGE(0, 0);
  __syncthreads();

#pragma unroll 1
  for (int tk = 0; tk < nt; ++tk) {
    const int kv0 = tk * 64;
    if (tk + 1 < nt) ATTN_STAGE(tk + 1, cur ^ 1);
    const u16* lKc = lK[cur];
    const u16* lVc = lV[cur];

    if (tk <= p) {
      // fused dual QK^T: each bk read feeds both tiles
      f32x4 scB[4] = {}, scA[4] = {};
#pragma unroll
      for (int n = 0; n < 4; ++n) {
#pragma unroll
        for (int kc = 0; kc < 4; ++kc) {
          const int row = n * 16 + lr;
          const int us = (kc * 4 + lg) ^ (row & 7);
          bf16x8 bk = *(const bf16x8*)&lKc[row * 128 + us * 8];
          scB[n] = __builtin_amdgcn_mfma_f32_16x16x32_bf16(qaB[kc], bk, scB[n], 0, 0, 0);
          scA[n] = __builtin_amdgcn_mfma_f32_16x16x32_bf16(qaA[kc], bk, scA[n], 0, 0, 0);
        }
      }
      SMPV(scB, oB, mB, lB, q0B);
      SMPV(scA, oA, mA, lA, q0A);
    } else {
      f32x4 scB[4] = {};
#pragma unroll
      for (int n = 0; n < 4; ++n) {
#pragma unroll
        for (int kc = 0; kc < 4; ++kc) {
          const int row = n * 16 + lr;
          const int us = (kc * 4 + lg) ^ (row & 7);
          bf16x8 bk = *(const bf16x8*)&lKc[row * 128 + us * 8];
          scB[n] = __builtin_amdgcn_mfma_f32_16x16x32_bf16(qaB[kc], bk, scB[n], 0, 0, 0);
        }
      }
      SMPV(scB, oB, mB, lB, q0B);
    }
    __syncthreads();
    cur ^= 1;
  }

#pragma unroll
  for (int nh = 0; nh < 8; ++nh)
#pragma unroll
    for (int r = 0; r < 4; ++r) {
      const int col = h * HDIM + nh * 16 + lr;
      ao[(size_t)(q0A + lg * 4 + r) * EQ + col] = f2bf(oA[nh][r] / lA[r]);
      ao[(size_t)(q0B + lg * 4 + r) * EQ + col] = f2bf(oB[nh][r] / lB[r]);
    }
}

// ---------------------------------------------------------------- launch
extern "C" void kernel_launch(void* const* d_in, const int* in_sizes, int n_in,
                              void* d_out, int out_size, void* d_ws, size_t ws_size,
                              hipStream_t stream) {
  (void)in_sizes; (void)n_in; (void)out_size; (void)ws_size;
  const float* x    = (const float*)d_in[0];
  const float* wq   = (const float*)d_in[1];
  const float* wk   = (const float*)d_in[2];
  const float* wv   = (const float*)d_in[3];
  const float* wo   = (const float*)d_in[4];
  const float* cosb = (const float*)d_in[7];
  const float* sinb = (const float*)d_in[8];
  const int*   sidx = (const int*)d_in[10];
  float* out = (float*)d_out;

  // workspace layout (weights no longer cast -- staged from fp32 in-GEMM)
  u16* ws  = (u16*)d_ws;
  u16* xb  = ws;                                  // 2048*4096
  u16* qb  = xb  + (size_t)S_LEN * DM;            // 2048*4096
  u16* kb  = qb  + (size_t)S_LEN * EQ;            // 2048*1024
  u16* vb  = kb  + (size_t)S_LEN * EKV;           // 2048*1024
  u16* vtb = vb  + (size_t)S_LEN * EKV;           // 1024*2048
  u16* aob = vtb + (size_t)S_LEN * EKV;           // 2048*4096

  cast_x<<<1024, 256, 0, stream>>>(x, xb);
  // fused QKV projection: B = [wq;wk;wv] fp32, BM=128/BN=192 -> 32x16 = 512 blocks (2/CU)
  gemm2p<3, true><<<dim3(32, 16), 256, 0, stream>>>(xb, wq, wk, wv, qb, kb, vb, DM);
  rope_all<<<5120, 256, 0, stream>>>(qb, kb, cosb, sinb, sidx);
  transpose_v<<<dim3(EKV / 32, S_LEN / 32), dim3(32, 8), 0, stream>>>(vb, vtb);
  attn_fwd<<<dim3(16, NH), 256, 0, stream>>>(qb, kb, vtb, aob);
  // O projection: B = wo fp32, BM=128/BN=128 -> 32x16 = 512 blocks (2/CU)
  gemm2p<2, false><<<dim3(32, 16), 256, 0, stream>>>(aob, wo, nullptr, nullptr, out, nullptr, nullptr, EQ);
}